// Round 5
// baseline (85.726 us; speedup 1.0000x reference)
//
#include <hip/hip_runtime.h>

#define BATCH 8192
#define DIM 128
#define NREL 1000
#define MARGIN 1.0f
#define GRID 1400  // score blocks; 1400 = 175 * 8 (clean XCD swizzle)

// ws layout (4 B units): pA[8192] | pB[8192] | order[11264] | ctr[1]
#define WS_PA 0
#define WS_PB 8192
#define WS_ORDER 16384
#define WS_CTR 27648
#define ORDER_CAP 11264  // >= 2800 groups * 4; max padded total = 8192+3*1000

// Fused single-block counting sort: zero + count + pad-scan + init + scatter.
__global__ __launch_bounds__(1024) void sort_kernel(const int* __restrict__ r_idx,
                                                    int* __restrict__ order,
                                                    int* __restrict__ ctr) {
  __shared__ int s_cnt[1024];
  __shared__ int s_cur[1024];
  __shared__ int s_wsum[16];
  const int tid = threadIdx.x, lane = tid & 63, wave = tid >> 6;
  if (tid == 0) ctr[0] = 0;  // reset done-counter for score epilogue
  s_cnt[tid] = 0;
  __syncthreads();
  int my[8];
#pragma unroll
  for (int k = 0; k < 8; ++k) {
    my[k] = r_idx[tid + k * 1024];
    atomicAdd(&s_cnt[my[k]], 1);
  }
  __syncthreads();
  // exclusive scan of counts padded to multiples of 4
  const int c = (s_cnt[tid] + 3) & ~3;
  int v = c;
#pragma unroll
  for (int o = 1; o < 64; o <<= 1) {
    int u = __shfl_up(v, o, 64);
    if (lane >= o) v += u;
  }
  if (lane == 63) s_wsum[wave] = v;
  __syncthreads();
  int woff = 0;
  for (int w = 0; w < wave; ++w) woff += s_wsum[w];
  s_cur[tid] = woff + v - c;
  for (int i = tid; i < ORDER_CAP; i += 1024) order[i] = -1;
  __syncthreads();
#pragma unroll
  for (int k = 0; k < 8; ++k) {
    int p = atomicAdd(&s_cur[my[k]], 1);
    order[p] = tid + k * 1024;
  }
}

__device__ inline float2 dvec(const float* __restrict__ b, int c0) {
  float2 h = *(const float2*)(b + c0);
  float2 r = *(const float2*)(b + DIM + c0);
  float2 t = *(const float2*)(b + 2 * DIM + c0);
  return make_float2(fabsf(h.x + r.x - t.x), fabsf(h.y + r.y - t.y));
}

// 2 waves per 4-element same-relation group; wave half h covers rows
// h*64..h*64+63. XCD-swizzled block id: each XCD gets a CONTIGUOUS chunk of
// sorted groups, so same-relation blocks share that XCD's L2 (W reuse from
// L2 at 34.5 TB/s instead of L3). Fused final reduce via last-block-done.
__global__ __launch_bounds__(256) void score_kernel(
    const float* __restrict__ pos_b, const float* __restrict__ neg_b,
    const int* __restrict__ r_idx, const float* __restrict__ rel_emb,
    const int* __restrict__ order, float* __restrict__ pA,
    float* __restrict__ pB, int* __restrict__ ctr, float* __restrict__ out) {
  __shared__ float s_d[4][DIM][8];  // wave-private: [row][{p0..p3,n0..n3}]
  __shared__ int s_last;
  const int tid = threadIdx.x, lane = tid & 63, wave = tid >> 6;
  // bijective XCD swizzle: blocks round-robin XCDs by phys%8; give each XCD
  // a contiguous logical range. GRID = 175*8 exactly.
  const int phys = blockIdx.x;
  const int lb = (phys & 7) * (GRID / 8) + (phys >> 3);
  const int pair = wave >> 1, half = wave & 1;
  const int g = lb * 2 + pair;
  int4 es = *(const int4*)(order + g * 4);

  if (es.x >= 0) {  // wave-uniform
    const int c0 = lane * 2;
    const int r = r_idx[es.x];
    const bool v1 = es.y >= 0, v2 = es.z >= 0, v3 = es.w >= 0;
    const int e1 = v1 ? es.y : es.x, e2 = v2 ? es.z : es.x,
              e3 = v3 ? es.w : es.x;

    const float2 z = make_float2(0.f, 0.f);
    float2 dp0 = dvec(pos_b + (size_t)es.x * 3 * DIM, c0);
    float2 dn0 = dvec(neg_b + (size_t)es.x * 3 * DIM, c0);
    float2 dp1 = v1 ? dvec(pos_b + (size_t)e1 * 3 * DIM, c0) : z;
    float2 dn1 = v1 ? dvec(neg_b + (size_t)e1 * 3 * DIM, c0) : z;
    float2 dp2 = v2 ? dvec(pos_b + (size_t)e2 * 3 * DIM, c0) : z;
    float2 dn2 = v2 ? dvec(neg_b + (size_t)e2 * 3 * DIM, c0) : z;
    float2 dp3 = v3 ? dvec(pos_b + (size_t)e3 * 3 * DIM, c0) : z;
    float2 dn3 = v3 ? dvec(neg_b + (size_t)e3 * 3 * DIM, c0) : z;

    *(float4*)&s_d[wave][c0][0]     = make_float4(dp0.x, dp1.x, dp2.x, dp3.x);
    *(float4*)&s_d[wave][c0][4]     = make_float4(dn0.x, dn1.x, dn2.x, dn3.x);
    *(float4*)&s_d[wave][c0 + 1][0] = make_float4(dp0.y, dp1.y, dp2.y, dp3.y);
    *(float4*)&s_d[wave][c0 + 1][4] = make_float4(dn0.y, dn1.y, dn2.y, dn3.y);
    // wave-private LDS region: in-wave lgkmcnt ordering suffices

    const int colb = (lane & 31) * 4;
    const int rsel = lane >> 5;
    const int rowbase = half * 64;
    const float* W = rel_emb + (size_t)r * (DIM * DIM) +
                     (size_t)(rowbase + rsel) * DIM + colb;

    float4 fz = make_float4(0.f, 0.f, 0.f, 0.f);
    float4 ap0 = fz, ap1 = fz, ap2 = fz, ap3 = fz;
    float4 an0 = fz, an1 = fz, an2 = fz, an3 = fz;
#pragma unroll 4
    for (int it = 0; it < 32; ++it) {
      float4 wv = *(const float4*)(W + (size_t)(it * 2) * DIM);
      const int row = rowbase + it * 2 + rsel;
      float4 ddp = *(const float4*)&s_d[wave][row][0];
      float4 ddn = *(const float4*)&s_d[wave][row][4];
      ap0.x = fmaf(ddp.x, wv.x, ap0.x); ap0.y = fmaf(ddp.x, wv.y, ap0.y);
      ap0.z = fmaf(ddp.x, wv.z, ap0.z); ap0.w = fmaf(ddp.x, wv.w, ap0.w);
      ap1.x = fmaf(ddp.y, wv.x, ap1.x); ap1.y = fmaf(ddp.y, wv.y, ap1.y);
      ap1.z = fmaf(ddp.y, wv.z, ap1.z); ap1.w = fmaf(ddp.y, wv.w, ap1.w);
      ap2.x = fmaf(ddp.z, wv.x, ap2.x); ap2.y = fmaf(ddp.z, wv.y, ap2.y);
      ap2.z = fmaf(ddp.z, wv.z, ap2.z); ap2.w = fmaf(ddp.z, wv.w, ap2.w);
      ap3.x = fmaf(ddp.w, wv.x, ap3.x); ap3.y = fmaf(ddp.w, wv.y, ap3.y);
      ap3.z = fmaf(ddp.w, wv.z, ap3.z); ap3.w = fmaf(ddp.w, wv.w, ap3.w);
      an0.x = fmaf(ddn.x, wv.x, an0.x); an0.y = fmaf(ddn.x, wv.y, an0.y);
      an0.z = fmaf(ddn.x, wv.z, an0.z); an0.w = fmaf(ddn.x, wv.w, an0.w);
      an1.x = fmaf(ddn.y, wv.x, an1.x); an1.y = fmaf(ddn.y, wv.y, an1.y);
      an1.z = fmaf(ddn.y, wv.z, an1.z); an1.w = fmaf(ddn.y, wv.w, an1.w);
      an2.x = fmaf(ddn.z, wv.x, an2.x); an2.y = fmaf(ddn.z, wv.y, an2.y);
      an2.z = fmaf(ddn.z, wv.z, an2.z); an2.w = fmaf(ddn.z, wv.w, an2.w);
      an3.x = fmaf(ddn.w, wv.x, an3.x); an3.y = fmaf(ddn.w, wv.y, an3.y);
      an3.z = fmaf(ddn.w, wv.z, an3.z); an3.w = fmaf(ddn.w, wv.w, an3.w);
    }

    float s0 = 0.f, s1 = 0.f, s2 = 0.f, s3 = 0.f;
#define EPI(K, COMP)                                          \
    {                                                         \
      float4 dp4 = *(const float4*)&s_d[wave][colb + K][0];   \
      float4 dn4 = *(const float4*)&s_d[wave][colb + K][4];   \
      s0 += ap0.COMP * dp4.x - an0.COMP * dn4.x;              \
      s1 += ap1.COMP * dp4.y - an1.COMP * dn4.y;              \
      s2 += ap2.COMP * dp4.z - an2.COMP * dn4.z;              \
      s3 += ap3.COMP * dp4.w - an3.COMP * dn4.w;              \
    }
    EPI(0, x) EPI(1, y) EPI(2, z) EPI(3, w)
#undef EPI

#pragma unroll
    for (int o = 32; o > 0; o >>= 1) {
      s0 += __shfl_xor(s0, o, 64);
      s1 += __shfl_xor(s1, o, 64);
      s2 += __shfl_xor(s2, o, 64);
      s3 += __shfl_xor(s3, o, 64);
    }
    float* P = half ? pB : pA;
    if (lane == 0) {
      P[es.x] = s0;
      if (v1) P[es.y] = s1;
      if (v2) P[es.z] = s2;
      if (v3) P[es.w] = s3;
    }
  }

  // ---- fused final reduction: last block to finish sums all partials ----
  __syncthreads();
  if (tid == 0) {
    __threadfence();  // release: make this block's pA/pB visible device-wide
    s_last = (atomicAdd(ctr, 1) == GRID - 1);
  }
  __syncthreads();
  if (s_last) {
    __threadfence();  // acquire: invalidate stale cached pA/pB lines
    float acc = 0.f;
    for (int i = tid; i < BATCH; i += 256) {
      float v = MARGIN + pA[i] + pB[i];
      acc += (v > 0.f) ? v : 0.f;
    }
#pragma unroll
    for (int o = 32; o > 0; o >>= 1) acc += __shfl_xor(acc, o, 64);
    if (lane == 0) s_d[0][0][wave] = acc;
    __syncthreads();
    if (tid == 0)
      out[0] = (s_d[0][0][0] + s_d[0][0][1] + s_d[0][0][2] + s_d[0][0][3]) *
               (1.0f / BATCH);
  }
}

extern "C" void kernel_launch(void* const* d_in, const int* in_sizes, int n_in,
                              void* d_out, int out_size, void* d_ws, size_t ws_size,
                              hipStream_t stream) {
  const float* pos_b = (const float*)d_in[0];
  const float* neg_b = (const float*)d_in[1];
  const int* r_idx = (const int*)d_in[2];
  const float* rel_emb = (const float*)d_in[3];
  float* out = (float*)d_out;

  float* pA = (float*)d_ws + WS_PA;
  float* pB = (float*)d_ws + WS_PB;
  int* order = (int*)d_ws + WS_ORDER;
  int* ctr = (int*)d_ws + WS_CTR;

  sort_kernel<<<1, 1024, 0, stream>>>(r_idx, order, ctr);
  score_kernel<<<GRID, 256, 0, stream>>>(pos_b, neg_b, r_idx, rel_emb, order,
                                         pA, pB, ctr, out);
}

// Round 6
// 57.516 us; speedup vs baseline: 1.4905x; 1.4905x over previous
//
#include <hip/hip_runtime.h>

#define BATCH 8192
#define DIM 128
#define NREL 1000
#define MARGIN 1.0f
#define GRID 1904       // score blocks = max groups (1899) rounded to 8*238
#define ORDER_CAP 15232 // GRID * 8 slots

// ws layout (4 B units): partial[8192] | order[15232]
#define WS_PARTIAL 0
#define WS_ORDER 8192

// Fused single-block counting sort (pad runs to multiples of 8).
__global__ __launch_bounds__(1024) void sort_kernel(const int* __restrict__ r_idx,
                                                    int* __restrict__ order) {
  __shared__ int s_cnt[1024];
  __shared__ int s_cur[1024];
  __shared__ int s_wsum[16];
  const int tid = threadIdx.x, lane = tid & 63, wave = tid >> 6;
  s_cnt[tid] = 0;
  __syncthreads();
  int my[8];
#pragma unroll
  for (int k = 0; k < 8; ++k) {
    my[k] = r_idx[tid + k * 1024];
    atomicAdd(&s_cnt[my[k]], 1);
  }
  __syncthreads();
  const int c = (s_cnt[tid] + 7) & ~7;  // pad to multiple of 8
  int v = c;
#pragma unroll
  for (int o = 1; o < 64; o <<= 1) {
    int u = __shfl_up(v, o, 64);
    if (lane >= o) v += u;
  }
  if (lane == 63) s_wsum[wave] = v;
  __syncthreads();
  int woff = 0;
  for (int w = 0; w < wave; ++w) woff += s_wsum[w];
  s_cur[tid] = woff + v - c;
  for (int i = tid; i < ORDER_CAP; i += 1024) order[i] = -1;
  __syncthreads();
#pragma unroll
  for (int k = 0; k < 8; ++k) {
    int p = atomicAdd(&s_cur[my[k]], 1);
    order[p] = tid + k * 1024;
  }
}

__device__ inline float2 dvec(const float* __restrict__ b, int c0) {
  float2 h = *(const float2*)(b + c0);
  float2 r = *(const float2*)(b + DIM + c0);
  float2 t = *(const float2*)(b + 2 * DIM + c0);
  return make_float2(fabsf(h.x + r.x - t.x), fabsf(h.y + r.y - t.y));
}

// One block per 8-element same-relation group. Wave w covers W rows
// [32w, 32w+32); W is read ONCE per 8 elements (97 MB total vs R4's 180).
// Each 16 B W load feeds 64 FMAs. d-vectors staged in LDS [row][16]
// ({dp0..7, dn0..7}); 2-address broadcast reads in the hot loop.
__global__ __launch_bounds__(256) void score_kernel(
    const float* __restrict__ pos_b, const float* __restrict__ neg_b,
    const int* __restrict__ r_idx, const float* __restrict__ rel_emb,
    const int* __restrict__ order, float* __restrict__ partial) {
  __shared__ float s_d[DIM][16];
  __shared__ float s_ps[4][8];
  __shared__ int s_es[8];
  const int tid = threadIdx.x, lane = tid & 63, wave = tid >> 6;
  // bijective XCD swizzle (phys%8 = XCD round-robin): each XCD gets a
  // contiguous run of sorted groups -> W reuse served by its own L2.
  const int phys = blockIdx.x;
  const int g = (phys & 7) * (GRID / 8) + (phys >> 3);

  if (order[g * 8] < 0) return;  // empty group, block-uniform
  if (tid < 8) s_es[tid] = order[g * 8 + tid];
  __syncthreads();

  // ---- d-stage: wave w computes elements 2w, 2w+1 ----
  const int c0 = lane * 2;
  {
    const int a = s_es[2 * wave], b = s_es[2 * wave + 1];
    const bool va = a >= 0, vb = b >= 0;
    const int ia = va ? a : s_es[0], ib = vb ? b : s_es[0];
    const float2 z = make_float2(0.f, 0.f);
    float2 dpa = va ? dvec(pos_b + (size_t)ia * 3 * DIM, c0) : z;
    float2 dna = va ? dvec(neg_b + (size_t)ia * 3 * DIM, c0) : z;
    float2 dpb = vb ? dvec(pos_b + (size_t)ib * 3 * DIM, c0) : z;
    float2 dnb = vb ? dvec(neg_b + (size_t)ib * 3 * DIM, c0) : z;
    *(float2*)&s_d[c0][2 * wave]         = make_float2(dpa.x, dpb.x);
    *(float2*)&s_d[c0 + 1][2 * wave]     = make_float2(dpa.y, dpb.y);
    *(float2*)&s_d[c0][8 + 2 * wave]     = make_float2(dna.x, dnb.x);
    *(float2*)&s_d[c0 + 1][8 + 2 * wave] = make_float2(dna.y, dnb.y);
  }
  __syncthreads();

  // ---- main loop: wave's 32-row quarter, float4 W loads ----
  const int r = r_idx[s_es[0]];
  const int colb = (lane & 31) * 4;
  const int rsel = lane >> 5;
  const int rowbase = wave * 32;
  const float* W = rel_emb + (size_t)r * (DIM * DIM) +
                   (size_t)(rowbase + rsel) * DIM + colb;

  const float4 fz = make_float4(0.f, 0.f, 0.f, 0.f);
  float4 ap0 = fz, ap1 = fz, ap2 = fz, ap3 = fz;
  float4 ap4 = fz, ap5 = fz, ap6 = fz, ap7 = fz;
  float4 an0 = fz, an1 = fz, an2 = fz, an3 = fz;
  float4 an4 = fz, an5 = fz, an6 = fz, an7 = fz;

#define FMA4(ACC, D, WV)                    \
  ACC.x = fmaf(D, WV.x, ACC.x);             \
  ACC.y = fmaf(D, WV.y, ACC.y);             \
  ACC.z = fmaf(D, WV.z, ACC.z);             \
  ACC.w = fmaf(D, WV.w, ACC.w);

#pragma unroll 4
  for (int it = 0; it < 16; ++it) {
    float4 wv = *(const float4*)(W + (size_t)(it * 2) * DIM);
    const int row = rowbase + it * 2 + rsel;
    float4 ddp0 = *(const float4*)&s_d[row][0];   // 2-addr broadcast
    float4 ddp1 = *(const float4*)&s_d[row][4];
    float4 ddn0 = *(const float4*)&s_d[row][8];
    float4 ddn1 = *(const float4*)&s_d[row][12];
    FMA4(ap0, ddp0.x, wv) FMA4(ap1, ddp0.y, wv)
    FMA4(ap2, ddp0.z, wv) FMA4(ap3, ddp0.w, wv)
    FMA4(ap4, ddp1.x, wv) FMA4(ap5, ddp1.y, wv)
    FMA4(ap6, ddp1.z, wv) FMA4(ap7, ddp1.w, wv)
    FMA4(an0, ddn0.x, wv) FMA4(an1, ddn0.y, wv)
    FMA4(an2, ddn0.z, wv) FMA4(an3, ddn0.w, wv)
    FMA4(an4, ddn1.x, wv) FMA4(an5, ddn1.y, wv)
    FMA4(an6, ddn1.z, wv) FMA4(an7, ddn1.w, wv)
  }
#undef FMA4

  // ---- epilogue: s_e += colacc_e[col] * d_e[col] over this lane's 4 cols ----
  float s0 = 0.f, s1 = 0.f, s2 = 0.f, s3 = 0.f;
  float s4 = 0.f, s5 = 0.f, s6 = 0.f, s7 = 0.f;
#define EPI(K, COMP)                                         \
  {                                                          \
    float4 dp0 = *(const float4*)&s_d[colb + K][0];          \
    float4 dp1 = *(const float4*)&s_d[colb + K][4];          \
    float4 dn0 = *(const float4*)&s_d[colb + K][8];          \
    float4 dn1 = *(const float4*)&s_d[colb + K][12];         \
    s0 += ap0.COMP * dp0.x - an0.COMP * dn0.x;               \
    s1 += ap1.COMP * dp0.y - an1.COMP * dn0.y;               \
    s2 += ap2.COMP * dp0.z - an2.COMP * dn0.z;               \
    s3 += ap3.COMP * dp0.w - an3.COMP * dn0.w;               \
    s4 += ap4.COMP * dp1.x - an4.COMP * dn1.x;               \
    s5 += ap5.COMP * dp1.y - an5.COMP * dn1.y;               \
    s6 += ap6.COMP * dp1.z - an6.COMP * dn1.z;               \
    s7 += ap7.COMP * dp1.w - an7.COMP * dn1.w;               \
  }
  EPI(0, x) EPI(1, y) EPI(2, z) EPI(3, w)
#undef EPI

#pragma unroll
  for (int o = 32; o > 0; o >>= 1) {
    s0 += __shfl_xor(s0, o, 64);
    s1 += __shfl_xor(s1, o, 64);
    s2 += __shfl_xor(s2, o, 64);
    s3 += __shfl_xor(s3, o, 64);
    s4 += __shfl_xor(s4, o, 64);
    s5 += __shfl_xor(s5, o, 64);
    s6 += __shfl_xor(s6, o, 64);
    s7 += __shfl_xor(s7, o, 64);
  }
  if (lane == 0) {
    s_ps[wave][0] = s0; s_ps[wave][1] = s1;
    s_ps[wave][2] = s2; s_ps[wave][3] = s3;
    s_ps[wave][4] = s4; s_ps[wave][5] = s5;
    s_ps[wave][6] = s6; s_ps[wave][7] = s7;
  }
  __syncthreads();
  if (tid < 8) {
    const int e = s_es[tid];
    if (e >= 0)
      partial[e] = s_ps[0][tid] + s_ps[1][tid] + s_ps[2][tid] + s_ps[3][tid];
  }
}

__global__ __launch_bounds__(256) void reduce_kernel(const float* __restrict__ partial,
                                                     float* __restrict__ out) {
  float acc = 0.f;
  for (int i = threadIdx.x; i < BATCH; i += 256) {
    float v = MARGIN + partial[i];
    acc += (v > 0.f) ? v : 0.f;
  }
#pragma unroll
  for (int o = 32; o > 0; o >>= 1) acc += __shfl_xor(acc, o, 64);
  __shared__ float s[4];
  const int lane = threadIdx.x & 63, wave = threadIdx.x >> 6;
  if (lane == 0) s[wave] = acc;
  __syncthreads();
  if (threadIdx.x == 0) out[0] = (s[0] + s[1] + s[2] + s[3]) * (1.0f / BATCH);
}

extern "C" void kernel_launch(void* const* d_in, const int* in_sizes, int n_in,
                              void* d_out, int out_size, void* d_ws, size_t ws_size,
                              hipStream_t stream) {
  const float* pos_b = (const float*)d_in[0];
  const float* neg_b = (const float*)d_in[1];
  const int* r_idx = (const int*)d_in[2];
  const float* rel_emb = (const float*)d_in[3];
  float* out = (float*)d_out;

  float* partial = (float*)d_ws + WS_PARTIAL;
  int* order = (int*)d_ws + WS_ORDER;

  sort_kernel<<<1, 1024, 0, stream>>>(r_idx, order);
  score_kernel<<<GRID, 256, 0, stream>>>(pos_b, neg_b, r_idx, rel_emb, order,
                                         partial);
  reduce_kernel<<<1, 256, 0, stream>>>(partial, out);
}

// Round 7
// 43.969 us; speedup vs baseline: 1.9497x; 1.3081x over previous
//
#include <hip/hip_runtime.h>

#define BATCH 8192
#define DIM 128
#define NREL 1000
#define MARGIN 1.0f
#define GRID 1400        // 1400 = 175 * 8 -> bijective XCD swizzle
#define ORDER_CAP 11264  // >= max padded total (8192 + 3*1000 = 11192)

// ws layout (4 B units): pA[8192] | pB[8192] | order[11264]
#define WS_PA 0
#define WS_PB 8192
#define WS_ORDER 16384

// Fused single-block counting sort: zero + count + pad4-scan + init + scatter.
__global__ __launch_bounds__(1024) void sort_kernel(const int* __restrict__ r_idx,
                                                    int* __restrict__ order) {
  __shared__ int s_cnt[1024];
  __shared__ int s_cur[1024];
  __shared__ int s_wsum[16];
  const int tid = threadIdx.x, lane = tid & 63, wave = tid >> 6;
  s_cnt[tid] = 0;
  __syncthreads();
  int my[8];
#pragma unroll
  for (int k = 0; k < 8; ++k) {
    my[k] = r_idx[tid + k * 1024];
    atomicAdd(&s_cnt[my[k]], 1);
  }
  __syncthreads();
  const int c = (s_cnt[tid] + 3) & ~3;  // pad runs to multiple of 4
  int v = c;
#pragma unroll
  for (int o = 1; o < 64; o <<= 1) {
    int u = __shfl_up(v, o, 64);
    if (lane >= o) v += u;
  }
  if (lane == 63) s_wsum[wave] = v;
  __syncthreads();
  int woff = 0;
  for (int w = 0; w < wave; ++w) woff += s_wsum[w];
  s_cur[tid] = woff + v - c;
  for (int i = tid; i < ORDER_CAP; i += 1024) order[i] = -1;
  __syncthreads();
#pragma unroll
  for (int k = 0; k < 8; ++k) {
    int p = atomicAdd(&s_cur[my[k]], 1);
    order[p] = tid + k * 1024;
  }
}

__device__ inline float2 dvec(const float* __restrict__ b, int c0) {
  float2 h = *(const float2*)(b + c0);
  float2 r = *(const float2*)(b + DIM + c0);
  float2 t = *(const float2*)(b + 2 * DIM + c0);
  return make_float2(fabsf(h.x + r.x - t.x), fabsf(h.y + r.y - t.y));
}

// 2 waves per 4-element same-relation group; wave half h covers rows
// [64h, 64h+64). Wave-private LDS d-stage in LANE-MAJOR stride-80B layout:
//   lane l holds units {dp(row 2l), dn(2l), dp(2l+1), dn(2l+1)} at l*20 floats
// -> stage writes sweep all 8 bank-quads (conflict-free); hot-loop reads are
// 2-address broadcasts (conflict-free). Epilogue d comes from __shfl (no LDS).
__global__ __launch_bounds__(256) void score_kernel(
    const float* __restrict__ pos_b, const float* __restrict__ neg_b,
    const int* __restrict__ r_idx, const float* __restrict__ rel_emb,
    const int* __restrict__ order, float* __restrict__ pA,
    float* __restrict__ pB) {
  __shared__ float s_d[4][64 * 20];  // 5120 B per wave, 20.5 KB per block
  const int tid = threadIdx.x, lane = tid & 63, wave = tid >> 6;
  // bijective XCD swizzle: each XCD gets a contiguous run of sorted groups
  const int phys = blockIdx.x;
  const int lb = (phys & 7) * (GRID / 8) + (phys >> 3);
  const int pair = wave >> 1, half = wave & 1;
  const int g = lb * 2 + pair;
  int4 es = *(const int4*)(order + g * 4);
  if (es.x < 0) return;  // wave-uniform empty group

  const int c0 = lane * 2;
  const int r = r_idx[es.x];
  const bool v1 = es.y >= 0, v2 = es.z >= 0, v3 = es.w >= 0;
  const int e1 = v1 ? es.y : es.x, e2 = v2 ? es.z : es.x, e3 = v3 ? es.w : es.x;

  const float2 z = make_float2(0.f, 0.f);
  float2 dp0 = dvec(pos_b + (size_t)es.x * 3 * DIM, c0);
  float2 dn0 = dvec(neg_b + (size_t)es.x * 3 * DIM, c0);
  float2 dp1 = v1 ? dvec(pos_b + (size_t)e1 * 3 * DIM, c0) : z;
  float2 dn1 = v1 ? dvec(neg_b + (size_t)e1 * 3 * DIM, c0) : z;
  float2 dp2 = v2 ? dvec(pos_b + (size_t)e2 * 3 * DIM, c0) : z;
  float2 dn2 = v2 ? dvec(neg_b + (size_t)e2 * 3 * DIM, c0) : z;
  float2 dp3 = v3 ? dvec(pos_b + (size_t)e3 * 3 * DIM, c0) : z;
  float2 dn3 = v3 ? dvec(neg_b + (size_t)e3 * 3 * DIM, c0) : z;

  // stage: lane-major, stride 20 floats (80 B) -> writes hit quads 20l%32:
  // {0,20,8,28,16,4,24,12} across l&7 -> all 8 quads, conflict-free.
  {
    float* myd = &s_d[wave][lane * 20];
    *(float4*)(myd + 0)  = make_float4(dp0.x, dp1.x, dp2.x, dp3.x);  // dp row 2l
    *(float4*)(myd + 4)  = make_float4(dn0.x, dn1.x, dn2.x, dn3.x);  // dn row 2l
    *(float4*)(myd + 8)  = make_float4(dp0.y, dp1.y, dp2.y, dp3.y);  // dp row 2l+1
    *(float4*)(myd + 12) = make_float4(dn0.y, dn1.y, dn2.y, dn3.y);  // dn row 2l+1
  }
  // wave-private LDS: in-wave lgkmcnt ordering suffices, no barrier

  const int colb = (lane & 31) * 4;
  const int rsel = lane >> 5;
  const float* W = rel_emb + (size_t)r * (DIM * DIM) +
                   (size_t)(half * 64 + rsel) * DIM + colb;
  // d read ptr: row rr = half*64 + it*2 + rsel -> unit base (rr>>1)*20 + rsel*8
  const float* dptr = &s_d[wave][(half * 32) * 20 + rsel * 8];

  const float4 fz = make_float4(0.f, 0.f, 0.f, 0.f);
  float4 ap0 = fz, ap1 = fz, ap2 = fz, ap3 = fz;
  float4 an0 = fz, an1 = fz, an2 = fz, an3 = fz;

#define FMA4(ACC, D, WV)          \
  ACC.x = fmaf(D, WV.x, ACC.x);   \
  ACC.y = fmaf(D, WV.y, ACC.y);   \
  ACC.z = fmaf(D, WV.z, ACC.z);   \
  ACC.w = fmaf(D, WV.w, ACC.w);

#pragma unroll 8
  for (int it = 0; it < 32; ++it) {
    float4 wv = *(const float4*)(W + (size_t)(it * 2) * DIM);
    float4 ddp = *(const float4*)(dptr + it * 20);      // 2-addr broadcast
    float4 ddn = *(const float4*)(dptr + it * 20 + 4);  // 2-addr broadcast
    FMA4(ap0, ddp.x, wv) FMA4(ap1, ddp.y, wv)
    FMA4(ap2, ddp.z, wv) FMA4(ap3, ddp.w, wv)
    FMA4(an0, ddn.x, wv) FMA4(an1, ddn.y, wv)
    FMA4(an2, ddn.z, wv) FMA4(an3, ddn.w, wv)
  }
#undef FMA4

  // epilogue: lane (lam=lane&31) owns cols 4lam..4lam+3; d for those cols
  // lives in lanes 2lam (.x,.y) and 2lam+1 (.x,.y) registers -> __shfl.
  const int sl0 = (lane & 31) * 2, sl1 = sl0 + 1;
#define GET4(OUT0, OUT1, OUT2, OUT3, V)   \
  OUT0 = __shfl(V.x, sl0, 64);            \
  OUT1 = __shfl(V.y, sl0, 64);            \
  OUT2 = __shfl(V.x, sl1, 64);            \
  OUT3 = __shfl(V.y, sl1, 64);
  float a, b, c, d, e, f, gg, h;
  float s0, s1, s2, s3;
  GET4(a, b, c, d, dp0) GET4(e, f, gg, h, dn0)
  s0 = ap0.x * a + ap0.y * b + ap0.z * c + ap0.w * d -
       (an0.x * e + an0.y * f + an0.z * gg + an0.w * h);
  GET4(a, b, c, d, dp1) GET4(e, f, gg, h, dn1)
  s1 = ap1.x * a + ap1.y * b + ap1.z * c + ap1.w * d -
       (an1.x * e + an1.y * f + an1.z * gg + an1.w * h);
  GET4(a, b, c, d, dp2) GET4(e, f, gg, h, dn2)
  s2 = ap2.x * a + ap2.y * b + ap2.z * c + ap2.w * d -
       (an2.x * e + an2.y * f + an2.z * gg + an2.w * h);
  GET4(a, b, c, d, dp3) GET4(e, f, gg, h, dn3)
  s3 = ap3.x * a + ap3.y * b + ap3.z * c + ap3.w * d -
       (an3.x * e + an3.y * f + an3.z * gg + an3.w * h);
#undef GET4

#pragma unroll
  for (int o = 32; o > 0; o >>= 1) {
    s0 += __shfl_xor(s0, o, 64);
    s1 += __shfl_xor(s1, o, 64);
    s2 += __shfl_xor(s2, o, 64);
    s3 += __shfl_xor(s3, o, 64);
  }
  float* P = half ? pB : pA;
  if (lane == 0) {
    P[es.x] = s0;
    if (v1) P[es.y] = s1;
    if (v2) P[es.z] = s2;
    if (v3) P[es.w] = s3;
  }
}

__global__ __launch_bounds__(256) void reduce_kernel(const float* __restrict__ pA,
                                                     const float* __restrict__ pB,
                                                     float* __restrict__ out) {
  float acc = 0.f;
  for (int i = threadIdx.x; i < BATCH; i += 256) {
    float v = MARGIN + pA[i] + pB[i];
    acc += (v > 0.f) ? v : 0.f;
  }
#pragma unroll
  for (int o = 32; o > 0; o >>= 1) acc += __shfl_xor(acc, o, 64);
  __shared__ float s[4];
  const int lane = threadIdx.x & 63, wave = threadIdx.x >> 6;
  if (lane == 0) s[wave] = acc;
  __syncthreads();
  if (threadIdx.x == 0) out[0] = (s[0] + s[1] + s[2] + s[3]) * (1.0f / BATCH);
}

extern "C" void kernel_launch(void* const* d_in, const int* in_sizes, int n_in,
                              void* d_out, int out_size, void* d_ws, size_t ws_size,
                              hipStream_t stream) {
  const float* pos_b = (const float*)d_in[0];
  const float* neg_b = (const float*)d_in[1];
  const int* r_idx = (const int*)d_in[2];
  const float* rel_emb = (const float*)d_in[3];
  float* out = (float*)d_out;

  float* pA = (float*)d_ws + WS_PA;
  float* pB = (float*)d_ws + WS_PB;
  int* order = (int*)d_ws + WS_ORDER;

  sort_kernel<<<1, 1024, 0, stream>>>(r_idx, order);
  score_kernel<<<GRID, 256, 0, stream>>>(pos_b, neg_b, r_idx, rel_emb, order,
                                         pA, pB);
  reduce_kernel<<<1, 256, 0, stream>>>(pA, pB, out);
}